// Round 7
// baseline (18170.770 us; speedup 1.0000x reference)
//
#include <hip/hip_runtime.h>

// GRU scan T=512, B=128, H=512 fp32 — v9: two-tile software pipeline to hide
// the inter-wg sync chain (barrier RTT + skew + LLC h-reload) under compute.
//
// v8 post-mortem: 30.7 us/step, VALUBusy 28%, ~5-6 us real work -> ~80% of
// each step is the serialized chain [agent h-store drain -> barrier -> LLC
// h reload]. All waves idle across it. FETCH rose to 26 MB/step (agent loads
// always read through; 32-way h broadcast is algorithmic).
// v9: split each wg's 16 rows into two 8-row tiles A (rows 0-63) / B (rows
// 64-127) in DIFFERENT barrier groups (16 groups x 32 wgs). Schedule:
//   GEMM/reduce/epi/store/arm A ; GEMM/reduce/epi/store/arm B   (B's ~3 us
//   of VALU overlaps A's barrier convergence) ; restage x ; poll A (mostly
//   done) ; reload h_A ; poll B ; reload h_B.
// Weights depend only on the j-slice -> the b-split is free in registers
// (same 48-float AGPR bank). h reload = 1 global_load_dwordx4 sc0 sc1 per
// thread per tile (4x fewer bypass loads than v8). LDS 95 KB.
// Predicted: dur 15736 -> ~4500-7000 us, VALUBusy 28 -> 45-65%,
// FETCH ~flat 1.2-1.4e7 KB, WRITE ~2e5 KB.

#define TT 512
#define BB 128
#define HH 512
#define H3 1536
#define NWG 256
#define NTHR 1024

// LDS floats: XsA[0,4096) XsB[4096,8192) HsA[8192,12288) HsB[12288,16384)
// red f4 @16384: 256 rows x 7 f4 = [16384,23552) ; sums [23552,24320)
#define LDS_FLOATS 24320

typedef float f32x4_t __attribute__((ext_vector_type(4)));

__global__ __launch_bounds__(NTHR)
__attribute__((amdgpu_waves_per_eu(4, 4)))
void gru_scan(
    const float* __restrict__ x,
    const float* __restrict__ h0,
    const float* __restrict__ Wi,
    const float* __restrict__ bi,
    const float* __restrict__ Wh,
    const float* __restrict__ bhn,
    float* out,
    unsigned int* __restrict__ bars)
{
  __shared__ float lds[LDS_FLOATS];
  float*  XsA  = lds;
  float*  XsB  = lds + 4096;
  float*  HsA  = lds + 8192;
  float*  HsB  = lds + 12288;
  float4* red  = reinterpret_cast<float4*>(lds + 16384);
  float*  sums = lds + 23552;

  const int tid = threadIdx.x;
  const int n   = blockIdx.x;
  const int jt  = n & 31;            // 32 j-tiles of 16 cols
  const int j0  = jt * 16;
  const int btA = n >> 5;            // 0..7  -> rows btA*8   (rows 0-63)
  const int b0A = btA * 8;
  const int b0B = b0A + 64;          // tile B -> rows 64-127, group btA+8

  const int w   = tid >> 6;          // wave 0..15 ; 0-7 -> h@Wh, 8-15 -> x@Wi
  const int kg  = (tid >> 4) & 3;    // 4-way K split within wave
  const int jl  = tid & 15;          // column within j-tile
  const int kbase = (w & 7) * 64;    // K-slice of 64 per wave (per matrix)
  const bool isH = (w < 8);

  unsigned int* grpA = bars + btA * 32;        // 128 B apart
  unsigned int* grpB = bars + (btA + 8) * 32;

  // ---- weights -> AGPR bank: 48 regs/lane, once for all 512 steps --------
  float wa[48];
  {
    const float* __restrict__ W = isH ? Wh : Wi;
    #pragma unroll
    for (int m = 0; m < 4; ++m)
      #pragma unroll
      for (int kk = 0; kk < 4; ++kk) {
        const int k = kbase + m * 16 + kg * 4 + kk;
        #pragma unroll
        for (int g = 0; g < 3; ++g) {
          const float v = W[(size_t)k * H3 + g * HH + j0 + jl];
          asm volatile("v_accvgpr_write_b32 %0, %1"
                       : "=a"(wa[(m * 4 + kk) * 3 + g]) : "v"(v));
        }
      }
  }

  float* ys = out + BB * HH;

  // epilogue constants (128 active epi threads)
  float bir = 0.f, biz = 0.f, bin = 0.f, bhnv = 0.f;
  if (tid < 128) {
    const int jj = j0 + (tid & 15);
    bir  = bi[jj];
    biz  = bi[jj + HH];
    bin  = bi[jj + 2 * HH];
    bhnv = bhn[jj];
  }

  // ---- prologue staging: x[0] and h0 for both tiles (plain f4) -----------
  {
    const int r = tid >> 7;          // 0..7
    const int c = tid & 127;         // f4 col
    *(float4*)&XsA[r * 512 + c * 4] = ((const float4*)(x  + (size_t)(b0A + r) * HH))[c];
    *(float4*)&XsB[r * 512 + c * 4] = ((const float4*)(x  + (size_t)(b0B + r) * HH))[c];
    *(float4*)&HsA[r * 512 + c * 4] = ((const float4*)(h0 + (size_t)(b0A + r) * HH))[c];
    *(float4*)&HsB[r * 512 + c * 4] = ((const float4*)(h0 + (size_t)(b0B + r) * HH))[c];
  }
  __syncthreads();

  for (int t = 0; t < TT; ++t) {
    #pragma unroll
    for (int ph = 0; ph < 2; ++ph) {
      const float* Hsx = ph ? HsB : HsA;
      const float* Xsx = ph ? XsB : XsA;
      const int    b0  = ph ? b0B : b0A;

      // ---- GEMM: 2 quads of 4 rows; 384 fmacs/lane/phase ----------------
      {
        const float* __restrict__ S = (isH ? Hsx : Xsx) + kbase;
        #pragma unroll
        for (int q = 0; q < 2; ++q) {
          float a[4][3];
          #pragma unroll
          for (int r = 0; r < 4; ++r)
            #pragma unroll
            for (int g = 0; g < 3; ++g) a[r][g] = 0.f;

          #pragma unroll
          for (int m = 0; m < 4; ++m) {
            float wv[12];
            #pragma unroll
            for (int kk = 0; kk < 4; ++kk)
              #pragma unroll
              for (int g = 0; g < 3; ++g)
                asm volatile("v_accvgpr_read_b32 %0, %1"
                             : "=v"(wv[kk * 3 + g])
                             : "a"(wa[(m * 4 + kk) * 3 + g]));

            const float* Sm = S + m * 16 + kg * 4;
            const float4 v0 = *(const float4*)(Sm + (q * 4 + 0) * 512);
            const float4 v1 = *(const float4*)(Sm + (q * 4 + 1) * 512);
            const float4 v2 = *(const float4*)(Sm + (q * 4 + 2) * 512);
            const float4 v3 = *(const float4*)(Sm + (q * 4 + 3) * 512);
            #pragma unroll
            for (int g = 0; g < 3; ++g) {
              a[0][g] += v0.x*wv[0+g] + v0.y*wv[3+g] + v0.z*wv[6+g] + v0.w*wv[9+g];
              a[1][g] += v1.x*wv[0+g] + v1.y*wv[3+g] + v1.z*wv[6+g] + v1.w*wv[9+g];
              a[2][g] += v2.x*wv[0+g] + v2.y*wv[3+g] + v2.z*wv[6+g] + v2.w*wv[9+g];
              a[3][g] += v3.x*wv[0+g] + v3.y*wv[3+g] + v3.z*wv[6+g] + v3.w*wv[9+g];
            }
          }

          // in-register K reduction over the 4 kg groups
          #pragma unroll
          for (int r = 0; r < 4; ++r)
            #pragma unroll
            for (int g = 0; g < 3; ++g) {
              a[r][g] += __shfl_xor(a[r][g], 16);
              a[r][g] += __shfl_xor(a[r][g], 32);
            }

          if (kg == q) {
            float4* rp = red + (size_t)(w * 16 + jl) * 7 + q * 3;
            #pragma unroll
            for (int g = 0; g < 3; ++g)
              rp[g] = make_float4(a[0][g], a[1][g], a[2][g], a[3][g]);
          }
        }
      }
      __syncthreads();

      // ---- reduce 8 wave-partials per matrix (192 active of 256) --------
      if (tid < 256) {
        const int pm  = tid >> 7;        // 0=h-side, 1=x-side
        const int pq  = (tid >> 6) & 1;  // quad
        const int pg  = (tid >> 4) & 3;
        const int pjl = tid & 15;
        if (pg < 3) {
          float4 s = make_float4(0.f, 0.f, 0.f, 0.f);
          #pragma unroll
          for (int w2 = 0; w2 < 8; ++w2) {
            const float4 v = red[(size_t)((pm * 8 + w2) * 16 + pjl) * 7 + pq * 3 + pg];
            s.x += v.x; s.y += v.y; s.z += v.z; s.w += v.w;
          }
          *(float4*)&sums[(size_t)((pm * 16 + pjl) * 3 + pg) * 8 + pq * 4] = s;
        }
      }
      __syncthreads();

      // ---- fused gate epilogue + agent store h_t (128 threads) ----------
      if (tid < 128) {
        const int eb  = tid >> 4;        // 0..7
        const int jl2 = tid & 15;
        const int jj  = j0 + jl2;
        const float ghr = sums[((     jl2) * 3 + 0) * 8 + eb];
        const float ghz = sums[((     jl2) * 3 + 1) * 8 + eb];
        const float ghn = sums[((     jl2) * 3 + 2) * 8 + eb];
        const float gir = sums[((16 + jl2) * 3 + 0) * 8 + eb];
        const float giz = sums[((16 + jl2) * 3 + 1) * 8 + eb];
        const float gin = sums[((16 + jl2) * 3 + 2) * 8 + eb];

        const float gr = gir + ghr + bir;
        const float gz = giz + ghz + biz;
        const float r  = 1.f / (1.f + __expf(-gr));
        const float z  = 1.f / (1.f + __expf(-gz));
        const float pre = gin + bin + r * (ghn + bhnv);
        const float e2 = __expf(2.f * pre);
        const float nn = 1.f - 2.f / (e2 + 1.f);
        const float hpv = Hsx[eb * 512 + jj];          // staged h_{t-1}
        const float h = (1.f - z) * nn + z * hpv;

        const size_t o = (size_t)(b0 + eb) * HH + jj;
        __hip_atomic_store(ys + (size_t)t * BB * HH + o, h,
                           __ATOMIC_RELAXED, __HIP_MEMORY_SCOPE_AGENT);
        if (t == TT - 1) out[o] = h;
      }
      __syncthreads();   // drains vmcnt: h stores at LLC before arming
      if (tid == 0 && t + 1 < TT)
        __hip_atomic_fetch_add(ph ? grpB : grpA, 1u, __ATOMIC_RELEASE,
                               __HIP_MEMORY_SCOPE_AGENT);
      // phase B's GEMM (next ph iter) overlaps group A's barrier convergence
    }

    if (t + 1 < TT) {
      // ---- restage x(t+1) (plain f4, L2/HBM-stream) ----------------------
      const float* xn = x + (size_t)(t + 1) * BB * HH;
      const int r = tid >> 7;
      const int c = tid & 127;
      *(float4*)&XsA[r * 512 + c * 4] = ((const float4*)(xn + (size_t)(b0A + r) * HH))[c];
      *(float4*)&XsB[r * 512 + c * 4] = ((const float4*)(xn + (size_t)(b0B + r) * HH))[c];

      const unsigned int target = 32u * (unsigned int)(t + 1);
      const float* ysrow = ys + (size_t)t * BB * HH;

      // ---- wait group A (mostly converged already), reload h_A -----------
      if (tid == 0) {
        while (__hip_atomic_load(grpA, __ATOMIC_RELAXED,
                                 __HIP_MEMORY_SCOPE_AGENT) < target)
          __builtin_amdgcn_s_sleep(1);
      }
      __syncthreads();
      {
        const float* pa = ysrow + (size_t)(b0A + r) * HH + (c << 2);
        f32x4_t hv;
        asm volatile("global_load_dwordx4 %0, %1, off sc0 sc1\n\t"
                     "s_waitcnt vmcnt(0)"
                     : "=v"(hv) : "v"(pa) : "memory");
        *(f32x4_t*)&HsA[r * 512 + c * 4] = hv;
      }

      // ---- wait group B, reload h_B --------------------------------------
      if (tid == 0) {
        while (__hip_atomic_load(grpB, __ATOMIC_RELAXED,
                                 __HIP_MEMORY_SCOPE_AGENT) < target)
          __builtin_amdgcn_s_sleep(1);
      }
      __syncthreads();
      {
        const float* pb = ysrow + (size_t)(b0B + r) * HH + (c << 2);
        f32x4_t hv;
        asm volatile("global_load_dwordx4 %0, %1, off sc0 sc1\n\t"
                     "s_waitcnt vmcnt(0)"
                     : "=v"(hv) : "v"(pb) : "memory");
        *(f32x4_t*)&HsB[r * 512 + c * 4] = hv;
      }
      __syncthreads();   // Hs/Xs staged for step t+1
    }
  }
}

extern "C" void kernel_launch(void* const* d_in, const int* in_sizes, int n_in,
                              void* d_out, int out_size, void* d_ws, size_t ws_size,
                              hipStream_t stream) {
  const float* x   = (const float*)d_in[0];  // [T,B,H]
  const float* h0  = (const float*)d_in[1];  // [B,H]
  const float* Wi  = (const float*)d_in[2];  // [H,3H]
  const float* bi  = (const float*)d_in[3];  // [3H]
  const float* Wh  = (const float*)d_in[4];  // [H,3H]
  const float* bhn = (const float*)d_in[5];  // [H]
  float* out = (float*)d_out;                // [B,H] final + [T,B,H] ys
  unsigned int* bars = (unsigned int*)d_ws;  // 16 counters, 128 B apart

  hipMemsetAsync(d_ws, 0, 16 * 128, stream); // reset group counters

  void* args[] = {(void*)&x, (void*)&h0, (void*)&Wi, (void*)&bi,
                  (void*)&Wh, (void*)&bhn, (void*)&out, (void*)&bars};
  hipLaunchCooperativeKernel(reinterpret_cast<const void*>(gru_scan),
                             dim3(NWG), dim3(NTHR), args, 0, stream);
}

// Round 8
// 14020.897 us; speedup vs baseline: 1.2960x; 1.2960x over previous
//
#include <hip/hip_runtime.h>

// GRU scan T=512, B=128, H=512 fp32 — v10: wave-role split; the barrier
// chain is hidden under the h-independent x-projection.
//
// v8/v9 post-mortem: ~8 us/step VALU vs ~22-27 us of serialized sync chain
// [h-store drain -> arm -> poll RTT -> h reload at MALL latency]; v9's
// "pipeline" serialized phases inside the wg and pinned vmcnt(0) inside the
// reload asm -> regression. But x@Wi (half the FLOPs) never needed h.
// v10 structure (per step, 2 syncthreads):
//  phase 1 (concurrent):
//   - h-waves 0-7: lane0 polls group counter; reload WAVE-PRIVATE h slice
//     [16 rows x 64 k] (4 KB) into own LDS slab (no cross-wave dependency);
//     h-GEMM from slab -> shfl_xor K-reduce -> red[0:128)
//   - x-waves 8-15: gi(t+1) GEMM straight from GLOBAL x (L2-cached 64B
//     16-dup lane groups; no LDS staging, no waitcnt pinning)
//     -> red[128:256)
//  join1
//  phase 2: tid<256: reduce red_h + gi_buf[t&1] -> gates -> h_t -> agent
//           store (sc0sc1, proven v8); tid 512-767: reduce red_x ->
//           gi_buf[(t+1)&1]
//  join2 (drains stores) ; tid0 arms group counter (RELAXED agent add)
// Weights stay AGPR-banked (48/lane, v7 technique). Barrier groups: 8 b-tile
// groups x 32 wgs (v8 scheme). LDS 90 KB -> still 1 wg/CU.
// Predicted: dur 18170 -> 4000-7000 us, VALUBusy 24.6 -> 45-65%,
// FETCH 9.7e6 -> ~5e6 KB, WRITE 4.4e6 -> ~3e5 KB, conflicts ~2x down.

#define TT 512
#define BB 128
#define HH 512
#define H3 1536
#define NWG 256
#define NTHR 1024

// LDS floats: Hs 8*1024 = [0,8192) ; red f4 256x13 = [8192,21504) ;
//             gi 2*768 = [21504,23040)  -> 92160 B, 1 wg/CU.
#define LDS_FLOATS 23040

typedef float f32x4_t __attribute__((ext_vector_type(4)));

__global__ __launch_bounds__(NTHR)
__attribute__((amdgpu_waves_per_eu(4, 4)))
void gru_scan(
    const float* __restrict__ x,
    const float* __restrict__ h0,
    const float* __restrict__ Wi,
    const float* __restrict__ bi,
    const float* __restrict__ Wh,
    const float* __restrict__ bhn,
    float* out,
    unsigned int* __restrict__ bars)
{
  __shared__ float lds[LDS_FLOATS];
  float*  Hs  = lds;                          // 8 slabs x 1024 f (wave wh:
                                              //   [16 rows][16 f4] of k-slice)
  float4* red = (float4*)(lds + 8192);        // 256 rows x 13 f4 (pad 13)
  float*  gif = lds + 21504;                  // 2 x 768 f (gi double buffer)
  float4* gi4 = (float4*)gif;

  const int tid  = threadIdx.x;
  const int n    = blockIdx.x;
  const int jt   = n & 31;           // 32 j-tiles of 16 cols
  const int bt   = n >> 5;           // 8 b-tiles of 16 rows = barrier group
  const int j0   = jt * 16;
  const int b0   = bt * 16;

  const int w    = tid >> 6;         // wave 0..15; 0-7 h-side, 8-15 x-side
  const int lane = tid & 63;
  const int kg   = (tid >> 4) & 3;   // 4-way K split within wave
  const int jl   = tid & 15;         // column within j-tile
  const int wh   = w & 7;
  const int kbase = wh * 64;         // K-slice of 64 (per matrix)
  const bool isH = (w < 8);

  unsigned int* grp = bars + bt * 32;   // group counters 128 B apart

  // ---- weights -> AGPR bank: 48 regs/lane, once for all 512 steps --------
  float wa[48];
  {
    const float* __restrict__ W = isH ? Wh : Wi;
    #pragma unroll
    for (int m = 0; m < 4; ++m)
      #pragma unroll
      for (int kk = 0; kk < 4; ++kk) {
        const int k = kbase + m * 16 + kg * 4 + kk;
        #pragma unroll
        for (int g = 0; g < 3; ++g) {
          const float v = W[(size_t)k * H3 + g * HH + j0 + jl];
          asm volatile("v_accvgpr_write_b32 %0, %1"
                       : "=a"(wa[(m * 4 + kk) * 3 + g]) : "v"(v));
        }
      }
  }

  float* ys = out + BB * HH;

  // epilogue constants
  float bir = 0.f, biz = 0.f, bin = 0.f, bhnv = 0.f;
  if (tid < 256) {
    const int jj = j0 + (tid & 15);
    bir  = bi[jj];
    biz  = bi[jj + HH];
    bin  = bi[jj + 2 * HH];
    bhnv = bhn[jj];
  }

  // ---- prologue: h-waves stage h0 slab; x-waves compute gi(0) partials ---
  if (isH) {
    #pragma unroll
    for (int i = 0; i < 4; ++i) {
      const int flat = i * 64 + lane;          // f4 index in slab
      const int r = flat >> 4, cf4 = flat & 15;
      *(float4*)&Hs[wh * 1024 + flat * 4] =
          *(const float4*)(h0 + (size_t)(b0 + r) * HH + kbase + cf4 * 4);
    }
  } else {
    // gi(0) GEMM from global x[0]
    #pragma unroll
    for (int q = 0; q < 4; ++q) {
      float a[4][3];
      #pragma unroll
      for (int r = 0; r < 4; ++r)
        #pragma unroll
        for (int g = 0; g < 3; ++g) a[r][g] = 0.f;
      #pragma unroll
      for (int m = 0; m < 4; ++m) {
        float wv[12];
        #pragma unroll
        for (int kk = 0; kk < 4; ++kk)
          #pragma unroll
          for (int g = 0; g < 3; ++g)
            asm volatile("v_accvgpr_read_b32 %0, %1"
                         : "=v"(wv[kk * 3 + g]) : "a"(wa[(m * 4 + kk) * 3 + g]));
        const float* P = x + (size_t)(b0 + q * 4) * HH + kbase + m * 16 + kg * 4;
        const float4 v0 = *(const float4*)(P);
        const float4 v1 = *(const float4*)(P + HH);
        const float4 v2 = *(const float4*)(P + 2 * HH);
        const float4 v3 = *(const float4*)(P + 3 * HH);
        #pragma unroll
        for (int g = 0; g < 3; ++g) {
          a[0][g] += v0.x*wv[0+g] + v0.y*wv[3+g] + v0.z*wv[6+g] + v0.w*wv[9+g];
          a[1][g] += v1.x*wv[0+g] + v1.y*wv[3+g] + v1.z*wv[6+g] + v1.w*wv[9+g];
          a[2][g] += v2.x*wv[0+g] + v2.y*wv[3+g] + v2.z*wv[6+g] + v2.w*wv[9+g];
          a[3][g] += v3.x*wv[0+g] + v3.y*wv[3+g] + v3.z*wv[6+g] + v3.w*wv[9+g];
        }
      }
      #pragma unroll
      for (int r = 0; r < 4; ++r)
        #pragma unroll
        for (int g = 0; g < 3; ++g) {
          a[r][g] += __shfl_xor(a[r][g], 16);
          a[r][g] += __shfl_xor(a[r][g], 32);
        }
      if (kg == q) {
        float4* rp = red + (size_t)(w * 16 + jl) * 13 + q * 3;
        #pragma unroll
        for (int g = 0; g < 3; ++g)
          rp[g] = make_float4(a[0][g], a[1][g], a[2][g], a[3][g]);
      }
    }
  }
  __syncthreads();
  // reduce gi(0) partials -> gi_buf[0]
  if (tid >= 512 && tid < 768) {
    const int t9  = tid - 512;
    const int pjl = t9 >> 4;
    const int pg  = (t9 >> 2) & 3;
    const int pbq = t9 & 3;
    if (pg < 3) {
      float4 s = make_float4(0.f, 0.f, 0.f, 0.f);
      #pragma unroll
      for (int w2 = 0; w2 < 8; ++w2) {
        const float4 v = red[(size_t)((8 + w2) * 16 + pjl) * 13 + pbq * 3 + pg];
        s.x += v.x; s.y += v.y; s.z += v.z; s.w += v.w;
      }
      gi4[(pbq * 3 + pg) * 16 + pjl] = s;
    }
  }
  __syncthreads();

  // ======================= main scan loop ================================
  for (int t = 0; t < TT; ++t) {
    // -------- phase 1: h-chain (waves 0-7) || gi(t+1) (waves 8-15) -------
    if (isH) {
      if (t > 0) {
        // wait for step t-1 of this b-group (lane0 polls, wave follows)
        if (lane == 0) {
          const unsigned int target = 32u * (unsigned int)t;
          while (__hip_atomic_load(grp, __ATOMIC_RELAXED,
                                   __HIP_MEMORY_SCOPE_AGENT) < target)
            __builtin_amdgcn_s_sleep(2);
        }
        // reload THIS wave's private h slice [16 rows][kbase..kbase+64)
        const float* src = ys + (size_t)(t - 1) * BB * HH;
        #pragma unroll
        for (int i = 0; i < 4; ++i) {
          const int flat = i * 64 + lane;
          const int r = flat >> 4, cf4 = flat & 15;
          const float* p = src + (size_t)(b0 + r) * HH + kbase + cf4 * 4;
          f32x4_t hv;
          asm volatile("global_load_dwordx4 %0, %1, off sc0 sc1"
                       : "=v"(hv) : "v"(p));
          *(f32x4_t*)&Hs[wh * 1024 + flat * 4] = hv;
        }
      }
      // h-GEMM from own slab (slab layout: [row r][f4 c] at r*64 + c*4)
      const float* S = Hs + wh * 1024;
      #pragma unroll
      for (int q = 0; q < 4; ++q) {
        float a[4][3];
        #pragma unroll
        for (int r = 0; r < 4; ++r)
          #pragma unroll
          for (int g = 0; g < 3; ++g) a[r][g] = 0.f;
        #pragma unroll
        for (int m = 0; m < 4; ++m) {
          float wv[12];
          #pragma unroll
          for (int kk = 0; kk < 4; ++kk)
            #pragma unroll
            for (int g = 0; g < 3; ++g)
              asm volatile("v_accvgpr_read_b32 %0, %1"
                           : "=v"(wv[kk * 3 + g]) : "a"(wa[(m * 4 + kk) * 3 + g]));
          const int cb = (m * 4 + kg) * 4;     // float offset of f4 in row
          const float4 v0 = *(const float4*)&S[(q * 4 + 0) * 64 + cb];
          const float4 v1 = *(const float4*)&S[(q * 4 + 1) * 64 + cb];
          const float4 v2 = *(const float4*)&S[(q * 4 + 2) * 64 + cb];
          const float4 v3 = *(const float4*)&S[(q * 4 + 3) * 64 + cb];
          #pragma unroll
          for (int g = 0; g < 3; ++g) {
            a[0][g] += v0.x*wv[0+g] + v0.y*wv[3+g] + v0.z*wv[6+g] + v0.w*wv[9+g];
            a[1][g] += v1.x*wv[0+g] + v1.y*wv[3+g] + v1.z*wv[6+g] + v1.w*wv[9+g];
            a[2][g] += v2.x*wv[0+g] + v2.y*wv[3+g] + v2.z*wv[6+g] + v2.w*wv[9+g];
            a[3][g] += v3.x*wv[0+g] + v3.y*wv[3+g] + v3.z*wv[6+g] + v3.w*wv[9+g];
          }
        }
        #pragma unroll
        for (int r = 0; r < 4; ++r)
          #pragma unroll
          for (int g = 0; g < 3; ++g) {
            a[r][g] += __shfl_xor(a[r][g], 16);
            a[r][g] += __shfl_xor(a[r][g], 32);
          }
        if (kg == q) {
          float4* rp = red + (size_t)(w * 16 + jl) * 13 + q * 3;
          #pragma unroll
          for (int g = 0; g < 3; ++g)
            rp[g] = make_float4(a[0][g], a[1][g], a[2][g], a[3][g]);
        }
      }
    } else if (t + 1 < TT) {
      // x-side: gi(t+1) from global x (L2-cached; overlaps h barrier chain)
      const float* xt1 = x + (size_t)(t + 1) * BB * HH;
      #pragma unroll
      for (int q = 0; q < 4; ++q) {
        float a[4][3];
        #pragma unroll
        for (int r = 0; r < 4; ++r)
          #pragma unroll
          for (int g = 0; g < 3; ++g) a[r][g] = 0.f;
        #pragma unroll
        for (int m = 0; m < 4; ++m) {
          float wv[12];
          #pragma unroll
          for (int kk = 0; kk < 4; ++kk)
            #pragma unroll
            for (int g = 0; g < 3; ++g)
              asm volatile("v_accvgpr_read_b32 %0, %1"
                           : "=v"(wv[kk * 3 + g]) : "a"(wa[(m * 4 + kk) * 3 + g]));
          const float* P = xt1 + (size_t)(b0 + q * 4) * HH + kbase + m * 16 + kg * 4;
          const float4 v0 = *(const float4*)(P);
          const float4 v1 = *(const float4*)(P + HH);
          const float4 v2 = *(const float4*)(P + 2 * HH);
          const float4 v3 = *(const float4*)(P + 3 * HH);
          #pragma unroll
          for (int g = 0; g < 3; ++g) {
            a[0][g] += v0.x*wv[0+g] + v0.y*wv[3+g] + v0.z*wv[6+g] + v0.w*wv[9+g];
            a[1][g] += v1.x*wv[0+g] + v1.y*wv[3+g] + v1.z*wv[6+g] + v1.w*wv[9+g];
            a[2][g] += v2.x*wv[0+g] + v2.y*wv[3+g] + v2.z*wv[6+g] + v2.w*wv[9+g];
            a[3][g] += v3.x*wv[0+g] + v3.y*wv[3+g] + v3.z*wv[6+g] + v3.w*wv[9+g];
          }
        }
        #pragma unroll
        for (int r = 0; r < 4; ++r)
          #pragma unroll
          for (int g = 0; g < 3; ++g) {
            a[r][g] += __shfl_xor(a[r][g], 16);
            a[r][g] += __shfl_xor(a[r][g], 32);
          }
        if (kg == q) {
          float4* rp = red + (size_t)(w * 16 + jl) * 13 + q * 3;
          #pragma unroll
          for (int g = 0; g < 3; ++g)
            rp[g] = make_float4(a[0][g], a[1][g], a[2][g], a[3][g]);
        }
      }
    }
    __syncthreads();   // join1: red_h + red_x + Hs slabs complete

    // -------- phase 2: epilogue (h) || gi-reduce (x) ---------------------
    if (tid < 256) {
      const int eb  = tid >> 4;
      const int jl2 = tid & 15;
      const int jj  = j0 + jl2;
      const int c   = eb & 3;
      const int bq3 = (eb >> 2) * 3;
      float ghr = 0.f, ghz = 0.f, ghn = 0.f;
      #pragma unroll
      for (int w2 = 0; w2 < 8; ++w2) {
        const float* rp = (const float*)&red[(size_t)(w2 * 16 + jl2) * 13 + bq3];
        ghr += rp[c];
        ghz += rp[4 + c];
        ghn += rp[8 + c];
      }
      const int p = (t & 1) * 768;
      const float gir = gif[p + (bq3 + 0) * 64 + jl2 * 4 + c];
      const float giz = gif[p + (bq3 + 1) * 64 + jl2 * 4 + c];
      const float gin = gif[p + (bq3 + 2) * 64 + jl2 * 4 + c];

      const float gr = gir + ghr + bir;
      const float gz = giz + ghz + biz;
      const float r  = 1.f / (1.f + __expf(-gr));
      const float z  = 1.f / (1.f + __expf(-gz));
      const float pre = gin + bin + r * (ghn + bhnv);
      const float e2 = __expf(2.f * pre);
      const float nn = 1.f - 2.f / (e2 + 1.f);
      // h_{t-1} from the slab holding column jj
      const float hpv = Hs[(jj >> 6) * 1024 + eb * 64 + (jj & 63)];
      const float h = (1.f - z) * nn + z * hpv;

      const size_t o = (size_t)(b0 + eb) * HH + jj;
      __hip_atomic_store(ys + (size_t)t * BB * HH + o, h,
                         __ATOMIC_RELAXED, __HIP_MEMORY_SCOPE_AGENT);
      if (t == TT - 1) out[o] = h;
    } else if (tid >= 512 && tid < 768 && t + 1 < TT) {
      const int t9  = tid - 512;
      const int pjl = t9 >> 4;
      const int pg  = (t9 >> 2) & 3;
      const int pbq = t9 & 3;
      if (pg < 3) {
        float4 s = make_float4(0.f, 0.f, 0.f, 0.f);
        #pragma unroll
        for (int w2 = 0; w2 < 8; ++w2) {
          const float4 v = red[(size_t)((8 + w2) * 16 + pjl) * 13 + pbq * 3 + pg];
          s.x += v.x; s.y += v.y; s.z += v.z; s.w += v.w;
        }
        gi4[((t + 1) & 1) * 192 + (pbq * 3 + pg) * 16 + pjl] = s;
      }
    }
    __syncthreads();   // join2: h stores drained (per-wave vmcnt) + LDS WAR

    if (tid == 0 && t + 1 < TT)
      __hip_atomic_fetch_add(grp, 1u, __ATOMIC_RELAXED,
                             __HIP_MEMORY_SCOPE_AGENT);
  }
}

extern "C" void kernel_launch(void* const* d_in, const int* in_sizes, int n_in,
                              void* d_out, int out_size, void* d_ws, size_t ws_size,
                              hipStream_t stream) {
  const float* x   = (const float*)d_in[0];  // [T,B,H]
  const float* h0  = (const float*)d_in[1];  // [B,H]
  const float* Wi  = (const float*)d_in[2];  // [H,3H]
  const float* bi  = (const float*)d_in[3];  // [3H]
  const float* Wh  = (const float*)d_in[4];  // [H,3H]
  const float* bhn = (const float*)d_in[5];  // [H]
  float* out = (float*)d_out;                // [B,H] final + [T,B,H] ys
  unsigned int* bars = (unsigned int*)d_ws;  // 8 counters, 128 B apart

  hipMemsetAsync(d_ws, 0, 8 * 128, stream);  // reset group counters

  void* args[] = {(void*)&x, (void*)&h0, (void*)&Wi, (void*)&bi,
                  (void*)&Wh, (void*)&bhn, (void*)&out, (void*)&bars};
  hipLaunchCooperativeKernel(reinterpret_cast<const void*>(gru_scan),
                             dim3(NWG), dim3(NTHR), args, 0, stream);
}